// Round 8
// baseline (436.482 us; speedup 1.0000x reference)
//
#include <hip/hip_runtime.h>
#include <hip/hip_bf16.h>
#include <math.h>

typedef __bf16 bf16x8 __attribute__((ext_vector_type(8)));
typedef float f32x4 __attribute__((ext_vector_type(4)));

#define SEQ 1500
#define CDIM 1280
#define NHEAD 20
#define DHEAD 64
#define NMLP 5120
#define QKVN 3840
#define VTLD 1504   // leading dim of transposed V (47*32)
#define APAD 68     // attention LDS stride

// packed operand layout: [tile128][kchunk32][row128][kw32] ; one chunk = 8KB
__device__ __forceinline__ size_t pidx(int row, int col, int K) {
  return (size_t)(row >> 7) * ((size_t)K * 128) + (size_t)(col >> 5) * 4096 +
         (size_t)(row & 127) * 32 + (col & 31);
}

#define GLOAD_LDS16(gp, lp)                                                    \
  __builtin_amdgcn_global_load_lds(                                            \
      (const __attribute__((address_space(1))) unsigned int*)(gp),             \
      (__attribute__((address_space(3))) unsigned int*)(lp), 16, 0, 0)

// ---------------- dtype detection: bf16 (flag=1) vs fp32 (flag=0) ----------
__global__ void detect_kernel(const unsigned int* __restrict__ xw,
                              int* __restrict__ flag) {
  __shared__ int cnt[256];
  const unsigned int w = xw[threadIdx.x];
  const unsigned int e = (w >> 7) & 0xFF;
  cnt[threadIdx.x] = (e >= 100 && e <= 150) ? 1 : 0;
  __syncthreads();
  for (int s = 128; s > 0; s >>= 1) {
    if (threadIdx.x < (unsigned)s) cnt[threadIdx.x] += cnt[threadIdx.x + s];
    __syncthreads();
  }
  if (threadIdx.x == 0) flag[0] = (cnt[0] >= 160) ? 1 : 0;
}

// ---------------- pack all small params into pb (bf16) ---------------------
__global__ __launch_bounds__(256) void pack_params_kernel(
    const void* bq, const void* bv, const void* bo, const void* g1,
    const void* be1, const void* g2, const void* be2, const void* b1,
    const void* b2, __bf16* __restrict__ pb, const int* __restrict__ flag) {
  const int isbf = flag[0];
  const int i = blockIdx.x * 256 + threadIdx.x;
  if (i >= 16640) return;
  auto ld = [&](const void* p, int j) -> float {
    return isbf ? (float)((const __bf16*)p)[j] : ((const float*)p)[j];
  };
  float v;
  if (i < 3840) {
    if (i < 1280) v = ld(bq, i);
    else if (i < 2560) v = 0.f;
    else v = ld(bv, i - 2560);
  } else if (i < 5120) v = ld(bo, i - 3840);
  else if (i < 6400) v = ld(g1, i - 5120);
  else if (i < 7680) v = ld(be1, i - 6400);
  else if (i < 8960) v = ld(g2, i - 7680);
  else if (i < 10240) v = ld(be2, i - 8960);
  else if (i < 15360) v = ld(b1, i - 10240);
  else v = ld(b2, i - 15360);
  pb[i] = (__bf16)v;
}

// ---------------- weight transpose -> PACKED B^T layout --------------------
// in (K,N) row-major -> out packed over strips of N: [n/128][k/32][128][32]
__device__ __forceinline__ void transpose_body(const void* in, __bf16* out,
                                               int K, int N, int isbf) {
  __shared__ __bf16 t[32][33];
  const int tx = threadIdx.x, ty = threadIdx.y;
  const int n0 = blockIdx.x * 32, k0 = blockIdx.y * 32;
  if (isbf) {
    const __bf16* s = (const __bf16*)in;
#pragma unroll
    for (int i = ty; i < 32; i += 8)
      t[i][tx] = s[(size_t)(k0 + i) * N + n0 + tx];
  } else {
    const float* s = (const float*)in;
#pragma unroll
    for (int i = ty; i < 32; i += 8)
      t[i][tx] = (__bf16)s[(size_t)(k0 + i) * N + n0 + tx];
  }
  __syncthreads();
#pragma unroll
  for (int i = ty; i < 32; i += 8)
    out[pidx(n0 + i, k0 + tx, K)] = t[tx][i];
}

__global__ __launch_bounds__(256) void transpose_kernel(const void* __restrict__ in,
                                                        __bf16* __restrict__ out,
                                                        int K, int N,
                                                        const int* __restrict__ flag) {
  transpose_body(in, out, K, N, flag[0]);
}

__global__ __launch_bounds__(256) void transpose3_kernel(const void* __restrict__ Wq,
                                                         const void* __restrict__ Wk,
                                                         const void* __restrict__ Wv,
                                                         __bf16* __restrict__ out,
                                                         const int* __restrict__ flag) {
  const void* in = blockIdx.z == 0 ? Wq : (blockIdx.z == 1 ? Wk : Wv);
  transpose_body(in, out + (size_t)blockIdx.z * CDIM * CDIM, CDIM, CDIM, flag[0]);
}

// ---------------- activation transpose: [SEQ][.] -> [N][VTLD] --------------
__global__ __launch_bounds__(256) void transpose_act_kernel(const __bf16* __restrict__ in,
                                                            __bf16* __restrict__ out,
                                                            int istride) {
  __shared__ __bf16 t[32][33];
  const int tx = threadIdx.x, ty = threadIdx.y;
  const int n0 = blockIdx.x * 32, k0 = blockIdx.y * 32;
#pragma unroll
  for (int i = ty; i < 32; i += 8) {
    const int k = k0 + i;
    t[i][tx] = (k < SEQ) ? in[(size_t)k * istride + n0 + tx] : (__bf16)0.f;
  }
  __syncthreads();
#pragma unroll
  for (int i = ty; i < 32; i += 8) {
    const int kk = k0 + tx;
    if (kk < VTLD) out[(size_t)(n0 + i) * VTLD + kk] = t[tx][i];
  }
}

// ---------------- layernorm: writes PACKED output (GEMM-A layout) ----------
__global__ __launch_bounds__(256) void ln_kernel(const void* __restrict__ X,
                                                 const __bf16* __restrict__ gamma,
                                                 const __bf16* __restrict__ beta,
                                                 __bf16* __restrict__ Y,
                                                 int xflag, const int* __restrict__ flag) {
  const int isf32 = xflag ? (flag[0] == 0) : 0;
  const int row = blockIdx.x;
  float v[5];
  float s = 0.f, s2 = 0.f;
#pragma unroll
  for (int i = 0; i < 5; ++i) {
    const int c = threadIdx.x + 256 * i;
    const size_t idx = (size_t)row * CDIM + c;
    v[i] = isf32 ? ((const float*)X)[idx] : (float)((const __bf16*)X)[idx];
    s += v[i];
    s2 += v[i] * v[i];
  }
  const int lane = threadIdx.x & 63, wv = threadIdx.x >> 6;
#pragma unroll
  for (int off = 32; off > 0; off >>= 1) {
    s += __shfl_down(s, off);
    s2 += __shfl_down(s2, off);
  }
  __shared__ float red[8];
  if (lane == 0) { red[wv] = s; red[4 + wv] = s2; }
  __syncthreads();
  s = red[0] + red[1] + red[2] + red[3];
  s2 = red[4] + red[5] + red[6] + red[7];
  const float mu = s * (1.f / CDIM);
  const float var = s2 * (1.f / CDIM) - mu * mu;
  const float rstd = rsqrtf(fmaxf(var, 0.f) + 1e-5f);
#pragma unroll
  for (int i = 0; i < 5; ++i) {
    const int c = threadIdx.x + 256 * i;
    Y[pidx(row, c, CDIM)] =
        (__bf16)((v[i] - mu) * rstd * (float)gamma[c] + (float)beta[c]);
  }
}

// ---------------- GEMM 128x128, BK=32 dbuf, PACKED operands ----------------
// A, Bt in packed layout. grid (mtiles, ntiles, nsplit).
// nsplit>1: fp32 row-major partials. packC!=0: bf16 out in packed layout.
__global__ __launch_bounds__(256) void gemm_kernel(
    const __bf16* __restrict__ A, const __bf16* __restrict__ Bt,
    const __bf16* __restrict__ bias, void* __restrict__ Cv,
    int M, int N, int K, int KS, int gelu, int nsplit, int packC) {
  __shared__ __bf16 As[2][128 * 32];
  __shared__ __bf16 Bs[2][128 * 32];
  const int bm = blockIdx.x, bn = blockIdx.y, sz = blockIdx.z;
  const int tid = threadIdx.x;
  const int lane = tid & 63, wave = tid >> 6;
  const int wm = (wave >> 1) * 64, wn = (wave & 1) * 64;
  const int l16 = lane & 15, kq = (lane >> 4) << 3;

  f32x4 acc[4][4];
  const f32x4 zero = {0.f, 0.f, 0.f, 0.f};
#pragma unroll
  for (int i = 0; i < 4; ++i)
#pragma unroll
    for (int j = 0; j < 4; ++j) acc[i][j] = zero;

  const __bf16* Apk = A + (size_t)bm * K * 128 + lane * 8;
  const __bf16* Bpk = Bt + (size_t)bn * K * 128 + lane * 8;

  const int kbeg = sz * KS;
  int kend = kbeg + KS;
  if (kend > K) kend = K;

  auto stage = [&](int b, int k0) {
    const size_t co = (size_t)(k0 >> 5) * 4096;
#pragma unroll
    for (int t = 0; t < 2; ++t) {
      const int seg = (t * 64 + wave * 16) * 32;
      GLOAD_LDS16(Apk + co + seg, &As[b][seg]);
      GLOAD_LDS16(Bpk + co + seg, &Bs[b][seg]);
    }
  };

  stage(0, kbeg);
  int buf = 0;
  for (int k0 = kbeg; k0 < kend; k0 += 32) {
    __syncthreads();                    // buf's loads landed; prior reads done
    if (k0 + 32 < kend) stage(buf ^ 1, k0 + 32);
    bf16x8 af[4], bfr[4];
#pragma unroll
    for (int i = 0; i < 4; ++i)
      af[i] = *(const bf16x8*)(&As[buf][(wm + i * 16 + l16) * 32 + kq]);
#pragma unroll
    for (int j = 0; j < 4; ++j)
      bfr[j] = *(const bf16x8*)(&Bs[buf][(wn + j * 16 + l16) * 32 + kq]);
#pragma unroll
    for (int i = 0; i < 4; ++i)
#pragma unroll
      for (int j = 0; j < 4; ++j)
        acc[i][j] = __builtin_amdgcn_mfma_f32_16x16x32_bf16(af[i], bfr[j],
                                                            acc[i][j], 0, 0, 0);
    buf ^= 1;
  }

  // epilogue: D[row][col], col = lane&15, row = (lane>>4)*4 + r
  const int rq4 = (lane >> 4) * 4;
  if (nsplit > 1) {
    float* P = (float*)Cv + (size_t)sz * M * N;
#pragma unroll
    for (int i = 0; i < 4; ++i)
#pragma unroll
      for (int r = 0; r < 4; ++r) {
        const int grow = bm * 128 + wm + i * 16 + rq4 + r;
        if (grow >= M) continue;
#pragma unroll
        for (int j = 0; j < 4; ++j) {
          const int gcol = bn * 128 + wn + j * 16 + l16;
          P[(size_t)grow * N + gcol] = acc[i][j][r];
        }
      }
  } else {
    __bf16* Cb = (__bf16*)Cv;
#pragma unroll
    for (int i = 0; i < 4; ++i)
#pragma unroll
      for (int r = 0; r < 4; ++r) {
        const int grow = bm * 128 + wm + i * 16 + rq4 + r;
        if (grow >= M) continue;
#pragma unroll
        for (int j = 0; j < 4; ++j) {
          const int gcol = bn * 128 + wn + j * 16 + l16;
          float vv = acc[i][j][r];
          if (bias) vv += (float)bias[gcol];
          if (gelu) vv = 0.5f * vv * (1.f + erff(vv * 0.70710678118654752f));
          if (packC) Cb[pidx(grow, gcol, N)] = (__bf16)vv;
          else       Cb[(size_t)grow * N + gcol] = (__bf16)vv;
        }
      }
  }
}

// ---------------- split-K reduce: out = resid + sum(P) + bias --------------
__global__ __launch_bounds__(256) void reduce_kernel(
    const float* __restrict__ P, const __bf16* __restrict__ bias,
    const void* __restrict__ resid, void* __restrict__ out,
    int MN, int N, int S, int residflagged, int outflagged,
    const int* __restrict__ flag) {
  const int i = blockIdx.x * 256 + threadIdx.x;
  if (i >= MN) return;
  float v = 0.f;
  for (int s = 0; s < S; ++s) v += P[(size_t)s * MN + i];
  v += (float)bias[i % N];
  if (resid) {
    const int rf32 = residflagged ? (flag[0] == 0) : 0;
    v += rf32 ? ((const float*)resid)[i] : (float)((const __bf16*)resid)[i];
  }
  const int outbf = outflagged ? flag[0] : 1;
  if (outbf) ((__bf16*)out)[i] = (__bf16)v;
  else       ((float*)out)[i] = v;
}

// ---------------- MFMA flash attention, split-KV ---------------------------
__global__ __launch_bounds__(256) void attn_mfma_kernel(
    const __bf16* __restrict__ Q,    // fused base (+0), row stride rs
    const __bf16* __restrict__ Kk,   // fused base + 1280, row stride rs
    const __bf16* __restrict__ Vt,   // [CDIM][VTLD]
    float* __restrict__ Opart,       // [2][SEQ][CDIM]
    float* __restrict__ ml,          // [2][NHEAD][SEQ][2]
    int rs) {
  const int h = blockIdx.y;
  const int q0 = blockIdx.x * 64;
  const int z = blockIdx.z;
  const int tid = threadIdx.x;
  const int wave = tid >> 6, lane = tid & 63;
  const int l16 = lane & 15, quad = lane >> 4;

  __shared__ __bf16 Ks[64 * APAD];
  __shared__ __bf16 Vs[64 * APAD];
  __shared__ __bf16 Ps[4][16 * APAD];

  bf16x8 qf[2];
  {
    int q = q0 + wave * 16 + l16;
    if (q > SEQ - 1) q = SEQ - 1;
    const __bf16* qp = Q + (size_t)q * rs + h * DHEAD + quad * 8;
    qf[0] = *(const bf16x8*)(qp);
    qf[1] = *(const bf16x8*)(qp + 32);
  }

  f32x4 oacc[4];
  const f32x4 zero = {0.f, 0.f, 0.f, 0.f};
#pragma unroll
  for (int jt = 0; jt < 4; ++jt) oacc[jt] = zero;
  float mrow[4], lrow[4];
#pragma unroll
  for (int r = 0; r < 4; ++r) { mrow[r] = -30000.f; lrow[r] = 0.f; }

  const int srow = tid >> 2;
  const int scol = (tid & 3) << 4;

  const __bf16* Kbase = Kk + h * DHEAD;
  const __bf16* Vbase = Vt + (size_t)(h * DHEAD + srow) * VTLD;

  for (int kt = z * 12; kt < z * 12 + 12; ++kt) {
    const int key0 = kt * 64;
    __syncthreads();
    {
      int gk = key0 + srow;
      if (gk > SEQ - 1) gk = SEQ - 1;
      const __bf16* kp = Kbase + (size_t)gk * rs + scol;
      *(bf16x8*)(&Ks[srow * APAD + scol]) = *(const bf16x8*)(kp);
      *(bf16x8*)(&Ks[srow * APAD + scol + 8]) = *(const bf16x8*)(kp + 8);
      const __bf16* vp = Vbase + key0 + scol;
      *(bf16x8*)(&Vs[srow * APAD + scol]) = *(const bf16x8*)(vp);
      *(bf16x8*)(&Vs[srow * APAD + scol + 8]) = *(const bf16x8*)(vp + 8);
    }
    __syncthreads();

    f32x4 s[4];
#pragma unroll
    for (int jt = 0; jt < 4; ++jt) s[jt] = zero;
#pragma unroll
    for (int jt = 0; jt < 4; ++jt)
#pragma unroll
      for (int ks = 0; ks < 2; ++ks) {
        const bf16x8 kf = *(const bf16x8*)(&Ks[(jt * 16 + l16) * APAD + ks * 32 + quad * 8]);
        s[jt] = __builtin_amdgcn_mfma_f32_16x16x32_bf16(qf[ks], kf, s[jt], 0, 0, 0);
      }

#pragma unroll
    for (int jt = 0; jt < 4; ++jt) {
      const int key = key0 + jt * 16 + l16;
#pragma unroll
      for (int r = 0; r < 4; ++r) {
        float sv = s[jt][r] * 0.125f;
        if (key >= SEQ) sv = -30000.f;
        s[jt][r] = sv;
      }
    }

#pragma unroll
    for (int r = 0; r < 4; ++r) {
      float tmax = fmaxf(fmaxf(s[0][r], s[1][r]), fmaxf(s[2][r], s[3][r]));
#pragma unroll
      for (int off = 8; off > 0; off >>= 1) tmax = fmaxf(tmax, __shfl_xor(tmax, off));
      const float mnew = fmaxf(mrow[r], tmax);
      const float alpha = __expf(mrow[r] - mnew);
      mrow[r] = mnew;
      lrow[r] *= alpha;
#pragma unroll
      for (int jt = 0; jt < 4; ++jt) oacc[jt][r] *= alpha;
#pragma unroll
      for (int jt = 0; jt < 4; ++jt) {
        const float p = __expf(s[jt][r] - mnew);
        lrow[r] += p;
        Ps[wave][(quad * 4 + r) * APAD + jt * 16 + l16] = (__bf16)p;
      }
    }

    bf16x8 pf[2];
    pf[0] = *(const bf16x8*)(&Ps[wave][l16 * APAD + quad * 8]);
    pf[1] = *(const bf16x8*)(&Ps[wave][l16 * APAD + 32 + quad * 8]);
#pragma unroll
    for (int jt = 0; jt < 4; ++jt)
#pragma unroll
      for (int ks = 0; ks < 2; ++ks) {
        const bf16x8 vf = *(const bf16x8*)(&Vs[(jt * 16 + l16) * APAD + ks * 32 + quad * 8]);
        oacc[jt] = __builtin_amdgcn_mfma_f32_16x16x32_bf16(pf[ks], vf, oacc[jt], 0, 0, 0);
      }
  }

  float* Oz = Opart + (size_t)z * SEQ * CDIM;
#pragma unroll
  for (int r = 0; r < 4; ++r) {
    float lt = lrow[r];
#pragma unroll
    for (int off = 8; off > 0; off >>= 1) lt += __shfl_xor(lt, off);
    const int q = q0 + wave * 16 + quad * 4 + r;
    if (q < SEQ) {
#pragma unroll
      for (int jt = 0; jt < 4; ++jt)
        Oz[(size_t)q * CDIM + h * DHEAD + jt * 16 + l16] = oacc[jt][r];
      if (l16 == 0) {
        const size_t mi = ((size_t)(z * NHEAD + h) * SEQ + q) * 2;
        ml[mi] = mrow[r];
        ml[mi + 1] = lt;
      }
    }
  }
}

// ---------------- combine the two kv-halves -> PACKED attn-out -------------
__global__ __launch_bounds__(256) void attn_combine_kernel(
    const float* __restrict__ Op, const float* __restrict__ ml,
    __bf16* __restrict__ O) {
  const int i = blockIdx.x * 256 + threadIdx.x;
  if (i >= SEQ * CDIM) return;
  const int q = i / CDIM;
  const int c = i % CDIM;
  const int h = c >> 6;
  const size_t m1i = ((size_t)h * SEQ + q) * 2;
  const size_t m2i = ((size_t)(NHEAD + h) * SEQ + q) * 2;
  const float m1 = ml[m1i], l1 = ml[m1i + 1];
  const float m2 = ml[m2i], l2 = ml[m2i + 1];
  const float M = fmaxf(m1, m2);
  const float e1 = __expf(m1 - M), e2 = __expf(m2 - M);
  const float v = (e1 * Op[i] + e2 * Op[(size_t)SEQ * CDIM + i]) /
                  (e1 * l1 + e2 * l2);
  O[pidx(q, c, CDIM)] = (__bf16)v;
}

// ---------------- launch ----------------
extern "C" void kernel_launch(void* const* d_in, const int* in_sizes, int n_in,
                              void* d_out, int out_size, void* d_ws, size_t ws_size,
                              hipStream_t stream) {
  const void* x   = d_in[0];
  const void* Wq  = d_in[1];
  const void* bq  = d_in[2];
  const void* Wk  = d_in[3];
  const void* Wv  = d_in[4];
  const void* bv  = d_in[5];
  const void* Wo  = d_in[6];
  const void* bo  = d_in[7];
  const void* g1  = d_in[8];
  const void* be1 = d_in[9];
  const void* g2  = d_in[10];
  const void* be2 = d_in[11];
  const void* W1  = d_in[12];
  const void* bm1 = d_in[13];
  const void* W2  = d_in[14];
  const void* bm2 = d_in[15];

  char* ws = (char*)d_ws;
  size_t off = 0;
  auto alloc = [&](size_t elems) {
    __bf16* p = (__bf16*)(ws + off);
    off += elems * sizeof(__bf16);
    return p;
  };
  __bf16* Wqkvt = alloc((size_t)QKVN * CDIM);     // packed Wq^T|Wk^T|Wv^T
  __bf16* Wot   = alloc((size_t)CDIM * CDIM);     // packed
  __bf16* W1t   = alloc((size_t)CDIM * NMLP);     // packed
  __bf16* W2t   = alloc((size_t)CDIM * NMLP);     // packed
  __bf16* qkvb  = alloc((size_t)SEQ * QKVN);      // fused q|k|v row-major
  __bf16* hb    = alloc((size_t)12 * 128 * CDIM); // packed: ln1 out / attn out
  __bf16* mb    = alloc((size_t)12 * 128 * NMLP); // packed mlp hidden; head=Vt
  __bf16* pb    = alloc(20480);                   // packed params
  off = (off + 15) & ~(size_t)15;
  float* pscr = (float*)(ws + off);               // O-partials / split-K partials
  off += (size_t)2 * SEQ * CDIM * sizeof(float);
  float* mlb = (float*)(ws + off);                // attn (m,l)
  off += (size_t)2 * NHEAD * SEQ * 2 * sizeof(float);
  int* flag = (int*)(ws + off);

  __bf16* vtb  = mb;                         // Vt[CDIM][VTLD] (dead before MLP1)
  __bf16* x1b  = qkvb;                       // x1 row-major (qkv dead after attn)
  __bf16* h2b  = qkvb + (size_t)2097152;     // ln2 out, packed (12*128*1280)

  __bf16* qkvbias = pb + 0;
  __bf16* bo_b  = pb + 3840;
  __bf16* g1_b  = pb + 5120;
  __bf16* be1_b = pb + 6400;
  __bf16* g2_b  = pb + 7680;
  __bf16* be2_b = pb + 8960;
  __bf16* b1_b  = pb + 10240;
  __bf16* b2_b  = pb + 15360;

  detect_kernel<<<1, 256, 0, stream>>>((const unsigned int*)x, flag);
  pack_params_kernel<<<65, 256, 0, stream>>>(bq, bv, bo, g1, be1, g2, be2,
                                             bm1, bm2, pb, flag);

  const dim3 tb(32, 8);
  transpose3_kernel<<<dim3(40, 40, 3), tb, 0, stream>>>(Wq, Wk, Wv, Wqkvt, flag);
  transpose_kernel<<<dim3(40, 40), tb, 0, stream>>>(Wo, Wot, CDIM, CDIM, flag);
  transpose_kernel<<<dim3(160, 40), tb, 0, stream>>>(W1, W1t, CDIM, NMLP, flag);
  transpose_kernel<<<dim3(40, 160), tb, 0, stream>>>(W2, W2t, NMLP, CDIM, flag);

  // h = LN1(x) -> packed hb
  ln_kernel<<<SEQ, 256, 0, stream>>>(x, g1_b, be1_b, hb, 1, flag);
  // qkv = h @ Wqkv^T + (bq|0|bv)  -> row-major [1500][3840]
  gemm_kernel<<<dim3(12, 30, 1), 256, 0, stream>>>(
      hb, Wqkvt, qkvbias, qkvb, SEQ, QKVN, CDIM, CDIM, 0, 1, 0);
  // Vt = V^T (V = qkvb col-block 2)
  transpose_act_kernel<<<dim3(40, 47), tb, 0, stream>>>(qkvb + 2560, vtb, QKVN);
  // attention: split-KV partials, then combine -> packed hb
  attn_mfma_kernel<<<dim3(24, NHEAD, 2), 256, 0, stream>>>(
      qkvb, qkvb + 1280, vtb, pscr, mlb, QKVN);
  attn_combine_kernel<<<7500, 256, 0, stream>>>(pscr, mlb, hb);
  // attn @ Wo (split-K=2, fp32 row-major partials)
  gemm_kernel<<<dim3(12, 10, 2), 256, 0, stream>>>(
      hb, Wot, nullptr, pscr, SEQ, CDIM, CDIM, 640, 0, 2, 0);
  // x1 = x + partials + bo  -> row-major x1b
  reduce_kernel<<<7500, 256, 0, stream>>>(pscr, bo_b, x, x1b,
                                          SEQ * CDIM, CDIM, 2, 1, 0, flag);
  // h2 = LN2(x1) -> packed h2b
  ln_kernel<<<SEQ, 256, 0, stream>>>(x1b, g2_b, be2_b, h2b, 0, flag);
  // m = gelu(h2 @ W1 + b1) -> PACKED mb (A-layout for MLP2)
  gemm_kernel<<<dim3(12, 40, 1), 256, 0, stream>>>(
      h2b, W1t, b1_b, mb, SEQ, NMLP, CDIM, CDIM, 1, 1, 1);
  // m @ W2 (split-K=2)
  gemm_kernel<<<dim3(12, 10, 2), 256, 0, stream>>>(
      mb, W2t, nullptr, pscr, SEQ, CDIM, NMLP, 2560, 0, 2, 0);
  // out = x1 + partials + b2 (output dtype per flag)
  reduce_kernel<<<7500, 256, 0, stream>>>(pscr, b2_b, x1b, d_out,
                                          SEQ * CDIM, CDIM, 2, 0, 1, flag);
}

// Round 9
// 362.849 us; speedup vs baseline: 1.2029x; 1.2029x over previous
//
#include <hip/hip_runtime.h>
#include <hip/hip_bf16.h>
#include <math.h>

typedef __bf16 bf16x8 __attribute__((ext_vector_type(8)));
typedef float f32x4 __attribute__((ext_vector_type(4)));

#define SEQ 1500
#define CDIM 1280
#define NHEAD 20
#define DHEAD 64
#define NMLP 5120
#define QKVN 3840
#define VTLD 1504   // leading dim of transposed V (47*32)
#define APAD 68     // attention LDS stride

#define GLOAD_LDS16(gp, lp)                                                    \
  __builtin_amdgcn_global_load_lds(                                            \
      (const __attribute__((address_space(1))) unsigned int*)(gp),             \
      (__attribute__((address_space(3))) unsigned int*)(lp), 16, 0, 0)

// ---------------- pack params; each block self-detects dtype ----------------
// layout: [0,3840) qkvbias (bq|0|bv) | 3840 bo | 5120 g1 | 6400 be1 |
//         7680 g2 | 8960 be2 | 10240 b1(5120) | 15360 b2
__global__ __launch_bounds__(256) void pack_params_kernel(
    const unsigned int* __restrict__ xw, const void* bq, const void* bv,
    const void* bo, const void* g1, const void* be1, const void* g2,
    const void* be2, const void* b1, const void* b2,
    __bf16* __restrict__ pb, int* __restrict__ flag) {
  __shared__ int cnt[256];
  const unsigned int w = xw[threadIdx.x];
  const unsigned int e = (w >> 7) & 0xFF;
  cnt[threadIdx.x] = (e >= 100 && e <= 150) ? 1 : 0;
  __syncthreads();
  for (int s = 128; s > 0; s >>= 1) {
    if (threadIdx.x < (unsigned)s) cnt[threadIdx.x] += cnt[threadIdx.x + s];
    __syncthreads();
  }
  const int isbf = (cnt[0] >= 160) ? 1 : 0;
  if (blockIdx.x == 0 && threadIdx.x == 0) flag[0] = isbf;
  const int i = blockIdx.x * 256 + threadIdx.x;
  if (i >= 16640) return;
  auto ld = [&](const void* p, int j) -> float {
    return isbf ? (float)((const __bf16*)p)[j] : ((const float*)p)[j];
  };
  float v;
  if (i < 3840) {
    if (i < 1280) v = ld(bq, i);
    else if (i < 2560) v = 0.f;
    else v = ld(bv, i - 2560);
  } else if (i < 5120) v = ld(bo, i - 3840);
  else if (i < 6400) v = ld(g1, i - 5120);
  else if (i < 7680) v = ld(be1, i - 6400);
  else if (i < 8960) v = ld(g2, i - 7680);
  else if (i < 10240) v = ld(be2, i - 8960);
  else if (i < 15360) v = ld(b1, i - 10240);
  else v = ld(b2, i - 15360);
  pb[i] = (__bf16)v;
}

// ---------------- fused weight transpose: all 6 weights, one launch --------
// out layout: plain (N,K) row-major (strided reads spread HBM channels - R8)
__device__ __forceinline__ void transpose_body(const void* in, __bf16* out,
                                               int K, int N, int isbf,
                                               int bx, int by) {
  __shared__ __bf16 t[32][33];
  const int tx = threadIdx.x, ty = threadIdx.y;
  const int n0 = bx * 32, k0 = by * 32;
  if (isbf) {
    const __bf16* s = (const __bf16*)in;
#pragma unroll
    for (int i = ty; i < 32; i += 8)
      t[i][tx] = s[(size_t)(k0 + i) * N + n0 + tx];
  } else {
    const float* s = (const float*)in;
#pragma unroll
    for (int i = ty; i < 32; i += 8)
      t[i][tx] = (__bf16)s[(size_t)(k0 + i) * N + n0 + tx];
  }
  __syncthreads();
#pragma unroll
  for (int i = ty; i < 32; i += 8)
    out[(size_t)(n0 + i) * K + k0 + tx] = t[tx][i];
}

__global__ __launch_bounds__(256) void transpose_all_kernel(
    const void* Wq, const void* Wk, const void* Wv, const void* Wo,
    const void* W1, const void* W2, __bf16* __restrict__ Wqkvt,
    __bf16* __restrict__ Wot, __bf16* __restrict__ W1t,
    __bf16* __restrict__ W2t, const int* __restrict__ flag) {
  const int id = blockIdx.x;
  const int isbf = flag[0];
  if (id < 6400) {                      // Wq|Wk|Wv|Wo : 4 x (40x40)
    const int w = id / 1600, r = id % 1600;
    const void* in = (w == 0) ? Wq : (w == 1) ? Wk : (w == 2) ? Wv : Wo;
    __bf16* out = (w < 3) ? (Wqkvt + (size_t)w * CDIM * CDIM) : Wot;
    transpose_body(in, out, CDIM, CDIM, isbf, r % 40, r / 40);
  } else if (id < 12800) {              // W1 : 160x40
    const int r = id - 6400;
    transpose_body(W1, W1t, CDIM, NMLP, isbf, r % 160, r / 160);
  } else {                              // W2 : 40x160
    const int r = id - 12800;
    transpose_body(W2, W2t, NMLP, CDIM, isbf, r % 40, r / 40);
  }
}

// ---------------- activation transpose: [SEQ][.] -> [N][VTLD] --------------
__global__ __launch_bounds__(256) void transpose_act_kernel(const __bf16* __restrict__ in,
                                                            __bf16* __restrict__ out,
                                                            int istride) {
  __shared__ __bf16 t[32][33];
  const int tx = threadIdx.x, ty = threadIdx.y;
  const int n0 = blockIdx.x * 32, k0 = blockIdx.y * 32;
#pragma unroll
  for (int i = ty; i < 32; i += 8) {
    const int k = k0 + i;
    t[i][tx] = (k < SEQ) ? in[(size_t)k * istride + n0 + tx] : (__bf16)0.f;
  }
  __syncthreads();
#pragma unroll
  for (int i = ty; i < 32; i += 8) {
    const int kk = k0 + tx;
    if (kk < VTLD) out[(size_t)(n0 + i) * VTLD + kk] = t[tx][i];
  }
}

// ---------------- layernorm 1 (row-major out); X dtype per flag ------------
__global__ __launch_bounds__(256) void ln_kernel(const void* __restrict__ X,
                                                 const __bf16* __restrict__ gamma,
                                                 const __bf16* __restrict__ beta,
                                                 __bf16* __restrict__ Y,
                                                 const int* __restrict__ flag) {
  const int isf32 = (flag[0] == 0);
  const int row = blockIdx.x;
  float v[5];
  float s = 0.f, s2 = 0.f;
#pragma unroll
  for (int i = 0; i < 5; ++i) {
    const int c = threadIdx.x + 256 * i;
    const size_t idx = (size_t)row * CDIM + c;
    v[i] = isf32 ? ((const float*)X)[idx] : (float)((const __bf16*)X)[idx];
    s += v[i];
    s2 += v[i] * v[i];
  }
  const int lane = threadIdx.x & 63, wv = threadIdx.x >> 6;
#pragma unroll
  for (int off = 32; off > 0; off >>= 1) {
    s += __shfl_down(s, off);
    s2 += __shfl_down(s2, off);
  }
  __shared__ float red[8];
  if (lane == 0) { red[wv] = s; red[4 + wv] = s2; }
  __syncthreads();
  s = red[0] + red[1] + red[2] + red[3];
  s2 = red[4] + red[5] + red[6] + red[7];
  const float mu = s * (1.f / CDIM);
  const float var = s2 * (1.f / CDIM) - mu * mu;
  const float rstd = rsqrtf(fmaxf(var, 0.f) + 1e-5f);
#pragma unroll
  for (int i = 0; i < 5; ++i) {
    const int c = threadIdx.x + 256 * i;
    Y[(size_t)row * CDIM + c] =
        (__bf16)((v[i] - mu) * rstd * (float)gamma[c] + (float)beta[c]);
  }
}

// ---------------- fused: x1 = x + sum(P) + bo ; h2 = LN2(x1) ----------------
__global__ __launch_bounds__(256) void resid_ln_kernel(
    const float* __restrict__ P, const __bf16* __restrict__ bo,
    const void* __restrict__ X, const __bf16* __restrict__ gamma,
    const __bf16* __restrict__ beta, __bf16* __restrict__ X1,
    __bf16* __restrict__ H2, const int* __restrict__ flag) {
  const int isf32 = (flag[0] == 0);
  const int row = blockIdx.x;
  const int MN = SEQ * CDIM;
  float v[5];
  float s = 0.f, s2 = 0.f;
#pragma unroll
  for (int i = 0; i < 5; ++i) {
    const int c = threadIdx.x + 256 * i;
    const size_t idx = (size_t)row * CDIM + c;
    const float xv = isf32 ? ((const float*)X)[idx] : (float)((const __bf16*)X)[idx];
    const float val = P[idx] + P[MN + idx] + (float)bo[c] + xv;
    X1[idx] = (__bf16)val;
    v[i] = val;
    s += val;
    s2 += val * val;
  }
  const int lane = threadIdx.x & 63, wv = threadIdx.x >> 6;
#pragma unroll
  for (int off = 32; off > 0; off >>= 1) {
    s += __shfl_down(s, off);
    s2 += __shfl_down(s2, off);
  }
  __shared__ float red[8];
  if (lane == 0) { red[wv] = s; red[4 + wv] = s2; }
  __syncthreads();
  s = red[0] + red[1] + red[2] + red[3];
  s2 = red[4] + red[5] + red[6] + red[7];
  const float mu = s * (1.f / CDIM);
  const float var = s2 * (1.f / CDIM) - mu * mu;
  const float rstd = rsqrtf(fmaxf(var, 0.f) + 1e-5f);
#pragma unroll
  for (int i = 0; i < 5; ++i) {
    const int c = threadIdx.x + 256 * i;
    H2[(size_t)row * CDIM + c] =
        (__bf16)((v[i] - mu) * rstd * (float)gamma[c] + (float)beta[c]);
  }
}

// ---------------- GEMM 64x128 tile, BK=64 (2 x 32 chunks), 2-barrier -------
// (R5 structure: best total). nsplit>1: fp32 partials, no epilogue.
__global__ __launch_bounds__(256) void gemm64_kernel(
    const __bf16* __restrict__ A, const __bf16* __restrict__ Bt,
    const __bf16* __restrict__ bias, void* __restrict__ Cv,
    int M, int N, int K, int KS, int gelu, int nsplit) {
  __shared__ __bf16 As[2][64 * 32];
  __shared__ __bf16 Bs[2][128 * 32];
  const int bm = blockIdx.x, bn = blockIdx.y, sz = blockIdx.z;
  const int tid = threadIdx.x;
  const int lane = tid & 63, wave = tid >> 6;
  const int l16 = lane & 15, kq = (lane >> 4) << 3;
  const int lrow = lane >> 2, lcol = (lane & 3) << 3;
  const int wn = wave * 32;

  f32x4 acc[4][2];
  const f32x4 zero = {0.f, 0.f, 0.f, 0.f};
#pragma unroll
  for (int i = 0; i < 4; ++i)
#pragma unroll
    for (int j = 0; j < 2; ++j) acc[i][j] = zero;

  const int kbeg = sz * KS;
  int kend = kbeg + KS;
  if (kend > K) kend = K;

  int ga = bm * 64 + wave * 16 + lrow;
  if (ga > M - 1) ga = M - 1;  // clamp: garbage rows never stored
  const __bf16* Ap = A + (size_t)ga * K + lcol;

  for (int k0 = kbeg; k0 < kend; k0 += 64) {
#pragma unroll
    for (int c = 0; c < 2; ++c)
      GLOAD_LDS16(Ap + k0 + c * 32, &As[c][wave * 512]);
#pragma unroll
    for (int c = 0; c < 2; ++c)
#pragma unroll
      for (int t = 0; t < 2; ++t) {
        const int seg = t * 4 + wave;
        const int gb = bn * 128 + seg * 16 + lrow;  // N multiple of 128
        GLOAD_LDS16(Bt + (size_t)gb * K + k0 + c * 32 + lcol, &Bs[c][seg * 512]);
      }
    __syncthreads();
    bf16x8 af[4][2], bfr[2][2];
#pragma unroll
    for (int i = 0; i < 4; ++i)
#pragma unroll
      for (int c = 0; c < 2; ++c)
        af[i][c] = *(const bf16x8*)(&As[c][(i * 16 + l16) * 32 + kq]);
#pragma unroll
    for (int j = 0; j < 2; ++j)
#pragma unroll
      for (int c = 0; c < 2; ++c)
        bfr[j][c] = *(const bf16x8*)(&Bs[c][(wn + j * 16 + l16) * 32 + kq]);
#pragma unroll
    for (int i = 0; i < 4; ++i)
#pragma unroll
      for (int j = 0; j < 2; ++j)
#pragma unroll
        for (int c = 0; c < 2; ++c)
          acc[i][j] = __builtin_amdgcn_mfma_f32_16x16x32_bf16(af[i][c], bfr[j][c],
                                                              acc[i][j], 0, 0, 0);
    __syncthreads();
  }

  const int rq4 = (lane >> 4) * 4;
  if (nsplit > 1) {
    float* P = (float*)Cv + (size_t)sz * M * N;
#pragma unroll
    for (int i = 0; i < 4; ++i)
#pragma unroll
      for (int r = 0; r < 4; ++r) {
        const int grow = bm * 64 + i * 16 + rq4 + r;
        if (grow >= M) continue;
#pragma unroll
        for (int j = 0; j < 2; ++j) {
          const int gcol = bn * 128 + wn + j * 16 + l16;
          P[(size_t)grow * N + gcol] = acc[i][j][r];
        }
      }
  } else {
    __bf16* Cb = (__bf16*)Cv;
#pragma unroll
    for (int i = 0; i < 4; ++i)
#pragma unroll
      for (int r = 0; r < 4; ++r) {
        const int grow = bm * 64 + i * 16 + rq4 + r;
        if (grow >= M) continue;
#pragma unroll
        for (int j = 0; j < 2; ++j) {
          const int gcol = bn * 128 + wn + j * 16 + l16;
          float vv = acc[i][j][r];
          if (bias) vv += (float)bias[gcol];
          if (gelu) vv = 0.5f * vv * (1.f + erff(vv * 0.70710678118654752f));
          Cb[(size_t)grow * N + gcol] = (__bf16)vv;
        }
      }
  }
}

// ---------------- GEMM 128x128, BK=64, dbuf, XCD swizzle (R7: best MLP1) ---
__global__ __launch_bounds__(256) void gemm128s_kernel(
    const __bf16* __restrict__ A, const __bf16* __restrict__ Bt,
    const __bf16* __restrict__ bias, __bf16* __restrict__ C,
    int M, int N, int K, int gelu, int mtiles) {
  __shared__ __bf16 As[2][2][128 * 32];
  __shared__ __bf16 Bs[2][2][128 * 32];

  const int id = blockIdx.x;
  const int xcd = id & 7;
  const int grp = id >> 3;
  const int bm = grp % mtiles;
  const int bn = (grp / mtiles) * 8 + xcd;
  if (bn >= (N >> 7)) return;

  const int tid = threadIdx.x;
  const int lane = tid & 63, wave = tid >> 6;
  const int wm = (wave >> 1) * 64, wn = (wave & 1) * 64;
  const int l16 = lane & 15, kq = (lane >> 4) << 3;
  const int lrow = lane >> 2, lcol = (lane & 3) << 3;

  f32x4 acc[4][4];
  const f32x4 zero = {0.f, 0.f, 0.f, 0.f};
#pragma unroll
  for (int i = 0; i < 4; ++i)
#pragma unroll
    for (int j = 0; j < 4; ++j) acc[i][j] = zero;

  const __bf16* Ap[2];
  const __bf16* Bp[2];
#pragma unroll
  for (int t = 0; t < 2; ++t) {
    int ga = bm * 128 + t * 64 + wave * 16 + lrow;
    if (ga > M - 1) ga = M - 1;
    Ap[t] = A + (size_t)ga * K + lcol;
    const int gb = bn * 128 + t * 64 + wave * 16 + lrow;
    Bp[t] = Bt + (size_t)gb * K + lcol;
  }

  auto stage = [&](int b, int k0) {
#pragma unroll
    for (int t = 0; t < 2; ++t)
#pragma unroll
      for (int c = 0; c < 2; ++c) {
        GLOAD_LDS16(Ap[t] + k0 + c * 32, &As[b][c][(t * 64 + wave * 16) * 32]);
        GLOAD_LDS16(Bp[t] + k0 + c * 32, &Bs[b][c][(t * 64 + wave * 16) * 32]);
      }
  };

  stage(0, 0);
  int buf = 0;
  for (int k0 = 0; k0 < K; k0 += 64) {
    __syncthreads();
    if (k0 + 64 < K) stage(buf ^ 1, k0 + 64);
    bf16x8 af[4][2], bfr[4][2];
#pragma unroll
    for (int i = 0; i < 4; ++i)
#pragma unroll
      for (int c = 0; c < 2; ++c)
        af[i][c] = *(const bf16x8*)(&As[buf][c][(wm + i * 16 + l16) * 32 + kq]);
#pragma unroll
    for (int j = 0; j < 4; ++j)
#pragma unroll
      for (int c = 0; c < 2; ++c)
        bfr[j][c] = *(const bf16x8*)(&Bs[buf][c][(wn + j * 16 + l16) * 32 + kq]);
#pragma unroll
    for (int i = 0; i < 4; ++i)
#pragma unroll
      for (int j = 0; j < 4; ++j)
#pragma unroll
        for (int c = 0; c < 2; ++c)
          acc[i][j] = __builtin_amdgcn_mfma_f32_16x16x32_bf16(af[i][c], bfr[j][c],
                                                              acc[i][j], 0, 0, 0);
    buf ^= 1;
  }

  const int rq4 = (lane >> 4) * 4;
#pragma unroll
  for (int i = 0; i < 4; ++i)
#pragma unroll
    for (int r = 0; r < 4; ++r) {
      const int grow = bm * 128 + wm + i * 16 + rq4 + r;
      if (grow >= M) continue;
#pragma unroll
      for (int j = 0; j < 4; ++j) {
        const int gcol = bn * 128 + wn + j * 16 + l16;
        float vv = acc[i][j][r];
        if (bias) vv += (float)bias[gcol];
        if (gelu) vv = 0.5f * vv * (1.f + erff(vv * 0.70710678118654752f));
        C[(size_t)grow * N + gcol] = (__bf16)vv;
      }
    }
}

// ---------------- final reduce: out = resid + sum(P) + bias ----------------
__global__ __launch_bounds__(256) void reduce_kernel(
    const float* __restrict__ P, const __bf16* __restrict__ bias,
    const __bf16* __restrict__ resid, void* __restrict__ out,
    int MN, int N, const int* __restrict__ flag) {
  const int i = blockIdx.x * 256 + threadIdx.x;
  if (i >= MN) return;
  const float v = P[i] + P[(size_t)MN + i] + (float)bias[i % N] + (float)resid[i];
  if (flag[0]) ((__bf16*)out)[i] = (__bf16)v;
  else         ((float*)out)[i] = v;
}

// ---------------- MFMA flash attention, split-KV ---------------------------
__global__ __launch_bounds__(256) void attn_mfma_kernel(
    const __bf16* __restrict__ Q,    // fused base (+0), row stride rs
    const __bf16* __restrict__ Kk,   // fused base + 1280, row stride rs
    const __bf16* __restrict__ Vt,   // [CDIM][VTLD]
    float* __restrict__ Opart,       // [2][SEQ][CDIM]
    float* __restrict__ ml,          // [2][NHEAD][SEQ][2]
    int rs) {
  const int h = blockIdx.y;
  const int q0 = blockIdx.x * 64;
  const int z = blockIdx.z;
  const int tid = threadIdx.x;
  const int wave = tid >> 6, lane = tid & 63;
  const int l16 = lane & 15, quad = lane >> 4;

  __shared__ __bf16 Ks[64 * APAD];
  __shared__ __bf16 Vs[64 * APAD];
  __shared__ __bf16 Ps[4][16 * APAD];

  bf16x8 qf[2];
  {
    int q = q0 + wave * 16 + l16;
    if (q > SEQ - 1) q = SEQ - 1;
    const __bf16* qp = Q + (size_t)q * rs + h * DHEAD + quad * 8;
    qf[0] = *(const bf16x8*)(qp);
    qf[1] = *(const bf16x8*)(qp + 32);
  }

  f32x4 oacc[4];
  const f32x4 zero = {0.f, 0.f, 0.f, 0.f};
#pragma unroll
  for (int jt = 0; jt < 4; ++jt) oacc[jt] = zero;
  float mrow[4], lrow[4];
#pragma unroll
  for (int r = 0; r < 4; ++r) { mrow[r] = -30000.f; lrow[r] = 0.f; }

  const int srow = tid >> 2;
  const int scol = (tid & 3) << 4;

  const __bf16* Kbase = Kk + h * DHEAD;
  const __bf16* Vbase = Vt + (size_t)(h * DHEAD + srow) * VTLD;

  for (int kt = z * 12; kt < z * 12 + 12; ++kt) {
    const int key0 = kt * 64;
    __syncthreads();
    {
      int gk = key0 + srow;
      if (gk > SEQ - 1) gk = SEQ - 1;
      const __bf16* kp = Kbase + (size_t)gk * rs + scol;
      *(bf16x8*)(&Ks[srow * APAD + scol]) = *(const bf16x8*)(kp);
      *(bf16x8*)(&Ks[srow * APAD + scol + 8]) = *(const bf16x8*)(kp + 8);
      const __bf16* vp = Vbase + key0 + scol;
      *(bf16x8*)(&Vs[srow * APAD + scol]) = *(const bf16x8*)(vp);
      *(bf16x8*)(&Vs[srow * APAD + scol + 8]) = *(const bf16x8*)(vp + 8);
    }
    __syncthreads();

    f32x4 s[4];
#pragma unroll
    for (int jt = 0; jt < 4; ++jt) s[jt] = zero;
#pragma unroll
    for (int jt = 0; jt < 4; ++jt)
#pragma unroll
      for (int ks = 0; ks < 2; ++ks) {
        const bf16x8 kf = *(const bf16x8*)(&Ks[(jt * 16 + l16) * APAD + ks * 32 + quad * 8]);
        s[jt] = __builtin_amdgcn_mfma_f32_16x16x32_bf16(qf[ks], kf, s[jt], 0, 0, 0);
      }

#pragma unroll
    for (int jt = 0; jt < 4; ++jt) {
      const int key = key0 + jt * 16 + l16;
#pragma unroll
      for (int r = 0; r < 4; ++r) {
        float sv = s[jt][r] * 0.125f;
        if (key >= SEQ) sv = -30000.f;
        s[jt][r] = sv;
      }
    }

#pragma unroll
    for (int r = 0; r < 4; ++r) {
      float tmax = fmaxf(fmaxf(s[0][r], s[1][r]), fmaxf(s[2][r], s[3][r]));
#pragma unroll
      for (int off = 8; off > 0; off >>= 1) tmax = fmaxf(tmax, __shfl_xor(tmax, off));
      const float mnew = fmaxf(mrow[r], tmax);
      const float alpha = __expf(mrow[r] - mnew);
      mrow[r] = mnew;
      lrow[r] *= alpha;
#pragma unroll
      for (int jt = 0; jt < 4; ++jt) oacc[jt][r] *= alpha;
#pragma unroll
      for (int jt = 0; jt < 4; ++jt) {
        const float p = __expf(s[jt][r] - mnew);
        lrow[r] += p;
        Ps[wave][(quad * 4 + r) * APAD + jt * 16 + l16] = (__bf16)p;
      }
    }

    bf16x8 pf[2];
    pf[0] = *(const bf16x8*)(&Ps[wave][l16 * APAD + quad * 8]);
    pf[1] = *(const bf16x8*)(&Ps[wave][l16 * APAD + 32 + quad * 8]);
#pragma unroll
    for (int jt = 0; jt < 4; ++jt)
#pragma unroll
      for (int ks = 0; ks < 2; ++ks) {
        const bf16x8 vf = *(const bf16x8*)(&Vs[(jt * 16 + l16) * APAD + ks * 32 + quad * 8]);
        oacc[jt] = __builtin_amdgcn_mfma_f32_16x16x32_bf16(pf[ks], vf, oacc[jt], 0, 0, 0);
      }
  }

  float* Oz = Opart + (size_t)z * SEQ * CDIM;
#pragma unroll
  for (int r = 0; r < 4; ++r) {
    float lt = lrow[r];
#pragma unroll
    for (int off = 8; off > 0; off >>= 1) lt += __shfl_xor(lt, off);
    const int q = q0 + wave * 16 + quad * 4 + r;
    if (q < SEQ) {
#pragma unroll
      for (int jt = 0; jt < 4; ++jt)
        Oz[(size_t)q * CDIM + h * DHEAD + jt * 16 + l16] = oacc[jt][r];
      if (l16 == 0) {
        const size_t mi = ((size_t)(z * NHEAD + h) * SEQ + q) * 2;
        ml[mi] = mrow[r];
        ml[mi + 1] = lt;
      }
    }
  }
}

// ---------------- combine the two kv-halves --------------------------------
__global__ __launch_bounds__(256) void attn_combine_kernel(
    const float* __restrict__ Op, const float* __restrict__ ml,
    __bf16* __restrict__ O) {
  const int i = blockIdx.x * 256 + threadIdx.x;
  if (i >= SEQ * CDIM) return;
  const int q = i / CDIM;
  const int h = (i % CDIM) >> 6;
  const size_t m1i = ((size_t)h * SEQ + q) * 2;
  const size_t m2i = ((size_t)(NHEAD + h) * SEQ + q) * 2;
  const float m1 = ml[m1i], l1 = ml[m1i + 1];
  const float m2 = ml[m2i], l2 = ml[m2i + 1];
  const float M = fmaxf(m1, m2);
  const float e1 = __expf(m1 - M), e2 = __expf(m2 - M);
  const float v = (e1 * Op[i] + e2 * Op[(size_t)SEQ * CDIM + i]) /
                  (e1 * l1 + e2 * l2);
  O[i] = (__bf16)v;
}

// ---------------- launch ----------------
extern "C" void kernel_launch(void* const* d_in, const int* in_sizes, int n_in,
                              void* d_out, int out_size, void* d_ws, size_t ws_size,
                              hipStream_t stream) {
  const void* x   = d_in[0];
  const void* Wq  = d_in[1];
  const void* bq  = d_in[2];
  const void* Wk  = d_in[3];
  const void* Wv  = d_in[4];
  const void* bv  = d_in[5];
  const void* Wo  = d_in[6];
  const void* bo  = d_in[7];
  const void* g1  = d_in[8];
  const void* be1 = d_in[9];
  const void* g2  = d_in[10];
  const void* be2 = d_in[11];
  const void* W1  = d_in[12];
  const void* bm1 = d_in[13];
  const void* W2  = d_in[14];
  const void* bm2 = d_in[15];

  char* ws = (char*)d_ws;
  size_t off = 0;
  auto alloc = [&](size_t elems) {
    __bf16* p = (__bf16*)(ws + off);
    off += elems * sizeof(__bf16);
    return p;
  };
  __bf16* Wqkvt = alloc((size_t)QKVN * CDIM);   // Wq^T|Wk^T|Wv^T
  __bf16* Wot   = alloc((size_t)CDIM * CDIM);
  __bf16* W1t   = alloc((size_t)CDIM * NMLP);
  __bf16* W2t   = alloc((size_t)CDIM * NMLP);
  __bf16* qkvb  = alloc((size_t)SEQ * QKVN);    // fused q|k|v; later x1|h2
  __bf16* hb    = alloc((size_t)SEQ * CDIM);    // ln1 out / attn out
  __bf16* mb    = alloc((size_t)SEQ * NMLP);    // mlp hidden; head = Vt
  __bf16* pb    = alloc(20480);                 // packed params
  off = (off + 15) & ~(size_t)15;
  float* pscr = (float*)(ws + off);             // O-partials / split-K partials
  off += (size_t)2 * SEQ * CDIM * sizeof(float);
  float* mlb = (float*)(ws + off);              // attn (m,l): 2 x 20 x 1500 x 2
  off += (size_t)2 * NHEAD * SEQ * 2 * sizeof(float);
  int* flag = (int*)(ws + off);

  __bf16* vtb  = mb;                         // Vt[CDIM][VTLD] (dead before MLP1)
  __bf16* x1b  = qkvb;                       // x1 (qkv dead after attention)
  __bf16* h2b  = qkvb + (size_t)SEQ * CDIM;  // ln2 out

  __bf16* qkvbias = pb + 0;
  __bf16* bo_b  = pb + 3840;
  __bf16* g1_b  = pb + 5120;
  __bf16* be1_b = pb + 6400;
  __bf16* g2_b  = pb + 7680;
  __bf16* be2_b = pb + 8960;
  __bf16* b1_b  = pb + 10240;
  __bf16* b2_b  = pb + 15360;

  // 1. pack params (self-detect dtype; writes flag)
  pack_params_kernel<<<65, 256, 0, stream>>>(
      (const unsigned int*)x, bq, bv, bo, g1, be1, g2, be2, bm1, bm2, pb, flag);
  // 2. all weight transposes in one launch
  transpose_all_kernel<<<19200, dim3(32, 8), 0, stream>>>(
      Wq, Wk, Wv, Wo, W1, W2, Wqkvt, Wot, W1t, W2t, flag);
  // 3. h = LN1(x)
  ln_kernel<<<SEQ, 256, 0, stream>>>(x, g1_b, be1_b, hb, flag);
  // 4. qkv = h @ Wqkv^T + (bq|0|bv)   [1500][3840], 720 blocks
  gemm64_kernel<<<dim3(24, 30, 1), 256, 0, stream>>>(
      hb, Wqkvt, qkvbias, qkvb, SEQ, QKVN, CDIM, CDIM, 0, 1);
  // 5. Vt = V^T
  transpose_act_kernel<<<dim3(40, 47), dim3(32, 8), 0, stream>>>(
      qkvb + 2560, vtb, QKVN);
  // 6. attention split-KV partials
  attn_mfma_kernel<<<dim3(24, NHEAD, 2), 256, 0, stream>>>(
      qkvb, qkvb + 1280, vtb, pscr, mlb, QKVN);
  // 7. combine -> hb
  attn_combine_kernel<<<7500, 256, 0, stream>>>(pscr, mlb, hb);
  // 8. attn @ Wo (split-K=2, fp32 partials), 480 blocks
  gemm64_kernel<<<dim3(24, 10, 2), 256, 0, stream>>>(
      hb, Wot, nullptr, pscr, SEQ, CDIM, CDIM, 640, 0, 2);
  // 9. fused: x1 = x + partials + bo ; h2 = LN2(x1)
  resid_ln_kernel<<<SEQ, 256, 0, stream>>>(pscr, bo_b, x, g2_b, be2_b,
                                           x1b, h2b, flag);
  // 10. m = gelu(h2 @ W1 + b1)  (R7 kernel: 128^2, BK=64 dbuf, XCD swizzle)
  gemm128s_kernel<<<12 * 40, 256, 0, stream>>>(
      h2b, W1t, b1_b, mb, SEQ, NMLP, CDIM, 1, 12);
  // 11. m @ W2 (split-K=2), 480 blocks
  gemm64_kernel<<<dim3(24, 10, 2), 256, 0, stream>>>(
      mb, W2t, nullptr, pscr, SEQ, CDIM, NMLP, 2560, 0, 2);
  // 12. out = x1 + partials + b2 (output dtype per flag)
  reduce_kernel<<<7500, 256, 0, stream>>>(pscr, b2_b, x1b, d_out,
                                          SEQ * CDIM, CDIM, flag);
}